// Round 2
// baseline (957.599 us; speedup 1.0000x reference)
//
#include <hip/hip_runtime.h>

#define CC    48
#define HH    160
#define WWID  160
#define NPIX  25600
#define KK    8

// ws float layout offsets
#define OFF_W0T   0        // 2304   w0t[c*48+o] = W0[o][c]
#define OFF_B0    2304     // 48
#define OFF_WRT   2352     // 9216   wrt[cp*192 + i] = WR[i][cp]
#define OFF_WLT   11568    // 9216   wlt[cp*192 + i] = WL[i][cp]
#define OFF_WKT   20784    // 576    wkt[c*12+r] = Wk[r][c]
#define OFF_BK    21360    // 12
#define OFF_EDGE  21372    // ints: 204800

__global__ void prep_kernel(const float* W0, const float* b0, const float* WL,
                            const float* WR, const float* Wk, const float* bk,
                            float* ws) {
    float* w0t  = ws + OFF_W0T;
    float* b0f  = ws + OFF_B0;
    float* wrt  = ws + OFF_WRT;
    float* wlt  = ws + OFF_WLT;
    float* wkt  = ws + OFF_WKT;
    float* bkf  = ws + OFF_BK;
    int t = blockIdx.x * 256 + threadIdx.x;
    int stride = gridDim.x * 256;
    for (int i = t; i < 2304; i += stride) { int c = i / 48, o = i % 48; w0t[i] = W0[o*48 + c]; }
    for (int i = t; i < 9216; i += stride) {
        int cp = i / 192, r = i % 192;
        wrt[i] = WR[r*48 + cp];
        wlt[i] = WL[r*48 + cp];
    }
    for (int i = t; i < 576; i += stride) { int c = i / 12, r = i % 12; wkt[i] = Wk[r*48 + c]; }
    for (int i = t; i < 48; i += stride) { b0f[i] = b0[i]; }
    for (int i = t; i < 12; i += stride) { bkf[i] = bk[i]; }
}

// ---------------- topk: per 32x32 window, 8 NN per pixel ----------------
__global__ __launch_bounds__(128) void topk_kernel(const float* h, int* edge) {
    __shared__ float fs[128][52];   // staged candidate features (52*4B row: 16B-aligned)
    __shared__ float sqs[128];
    int win = blockIdx.x >> 3, sub = blockIdx.x & 7;
    int wi = win / 5, wj = win % 5;
    int tid = threadIdx.x;
    int nl = sub * 128 + tid;              // own local pixel 0..1023
    int rn = nl >> 5, cn = nl & 31;
    int n = (wi*32 + rn) * WWID + (wj*32 + cn);

    float f[48];
    #pragma unroll
    for (int c = 0; c < 48; c++) f[c] = h[c*NPIX + n];

    float d8[8]; int i8[8];
    #pragma unroll
    for (int s = 0; s < 8; s++) { d8[s] = 3.0e38f; i8[s] = 0; }
    float dworst = 3.0e38f;

    for (int ch = 0; ch < 8; ch++) {
        __syncthreads();
        int ml = ch * 128 + tid;
        int mg = (wi*32 + (ml >> 5)) * WWID + (wj*32 + (ml & 31));
        float s = 0.f;
        #pragma unroll
        for (int c = 0; c < 48; c++) {
            float v = h[c*NPIX + mg];
            fs[tid][c] = v;
            s += v * v;
        }
        sqs[tid] = s;
        __syncthreads();

        for (int j = 0; j < 128; j++) {
            int ml2 = ch * 128 + j;
            int rm = ml2 >> 5, cm = ml2 & 31;
            int dr = rn - rm; dr = dr < 0 ? -dr : dr;
            int dc = cn - cm; dc = dc < 0 ? -dc : dc;
            if (dr <= 1 && dc <= 1) continue;   // local mask (incl. self)
            float dot = 0.f;
            #pragma unroll
            for (int c4 = 0; c4 < 12; c4++) {
                float4 q = *(const float4*)&fs[j][c4*4];
                dot += f[c4*4+0]*q.x + f[c4*4+1]*q.y + f[c4*4+2]*q.z + f[c4*4+3]*q.w;
            }
            float d = sqs[j] - 2.f * dot;       // own sq dropped: order-preserving
            if (d < dworst) {
                bool done = false;
                #pragma unroll
                for (int s2 = 0; s2 < 8; s2++) {
                    bool hit = (!done) && (d8[s2] == dworst);
                    if (hit) { d8[s2] = d; i8[s2] = ml2; done = true; }
                }
                dworst = d8[0];
                #pragma unroll
                for (int s2 = 1; s2 < 8; s2++) dworst = fmaxf(dworst, d8[s2]);
            }
        }
    }
    #pragma unroll
    for (int s = 0; s < 8; s++) {
        int ml2 = i8[s];
        int g = (wi*32 + (ml2 >> 5)) * WWID + (wj*32 + (ml2 & 31));
        edge[n*8 + s] = g;
    }
}

// ---------------- ecc: one lane per edge; writes 0.5*hNL into d_out ----------------
__global__ __launch_bounds__(128) void ecc_kernel(const float* h, const float* ws,
                                                  const int* edge, float* outp) {
    const float* w0t = ws + OFF_W0T;
    const float* b0f = ws + OFF_B0;
    const float* wrt = ws + OFF_WRT;
    const float* wlt = ws + OFF_WLT;
    const float* wkt = ws + OFF_WKT;
    const float* bkf = ws + OFF_BK;

    __shared__ float th_s[128][49];   // theta, lane-private row (stride 49: conflict-free rotate reads)

    int tid = threadIdx.x;
    int gt = blockIdx.x * 128 + tid;  // edge id = n*8+k
    int n = gt >> 3;
    int m = edge[gt];

    // phase 1: theta = LReLU(W0 @ label + b0), gamma; vertex kept in registers
    float v[48];
    float th[48];
    #pragma unroll
    for (int o = 0; o < 48; o++) th[o] = 0.f;
    float s2 = 0.f;
    for (int c = 0; c < 48; c++) {
        float vf = h[c*NPIX + m];
        float cf = h[c*NPIX + n];
        v[c] = vf;
        float lc = vf - cf;
        s2 += lc * lc;
        const float* wc = w0t + c*48;
        #pragma unroll
        for (int o = 0; o < 48; o++) th[o] = fmaf(wc[o], lc, th[o]);
    }
    float gamma = expf(-s2 / 10.0f);
    #pragma unroll
    for (int o = 0; o < 48; o++) {
        float x = th[o] + b0f[o];
        th_s[tid][o] = (x >= 0.f) ? x : 0.01f * x;
    }

    // kappa = Wk @ theta + bk
    float kap[12];
    #pragma unroll
    for (int r = 0; r < 12; r++) kap[r] = bkf[r];
    for (int c = 0; c < 48; c++) {
        float t = th_s[tid][c];
        const float* wkc = wkt + c*12;
        #pragma unroll
        for (int r = 0; r < 12; r++) kap[r] = fmaf(wkc[r], t, kap[r]);
    }

    // sR[3q+p] = sum_cp theta[(p+cp)%48] * vt_q[cp],  vt_q[cp] = sum_c v[c]*WR[4c+q][cp]
    float sr[12];
    #pragma unroll
    for (int r = 0; r < 12; r++) sr[r] = 0.f;
    for (int cp = 0; cp < 48; cp++) {
        int i1 = (cp + 1 < 48) ? cp + 1 : cp - 47;
        int i2 = (cp + 2 < 48) ? cp + 2 : cp - 46;
        float t0 = th_s[tid][cp], t1 = th_s[tid][i1], t2 = th_s[tid][i2];
        const float* wr = wrt + cp * 192;
        float vt0 = 0.f, vt1 = 0.f, vt2 = 0.f, vt3 = 0.f;
        #pragma unroll
        for (int c = 0; c < 48; c++) {
            float vc = v[c];
            vt0 = fmaf(wr[4*c+0], vc, vt0);
            vt1 = fmaf(wr[4*c+1], vc, vt1);
            vt2 = fmaf(wr[4*c+2], vc, vt2);
            vt3 = fmaf(wr[4*c+3], vc, vt3);
        }
        sr[0] = fmaf(t0, vt0, sr[0]); sr[1]  = fmaf(t1, vt0, sr[1]);  sr[2]  = fmaf(t2, vt0, sr[2]);
        sr[3] = fmaf(t0, vt1, sr[3]); sr[4]  = fmaf(t1, vt1, sr[4]);  sr[5]  = fmaf(t2, vt1, sr[5]);
        sr[6] = fmaf(t0, vt2, sr[6]); sr[7]  = fmaf(t1, vt2, sr[7]);  sr[8]  = fmaf(t2, vt2, sr[8]);
        sr[9] = fmaf(t0, vt3, sr[9]); sr[10] = fmaf(t1, vt3, sr[10]); sr[11] = fmaf(t2, vt3, sr[11]);
    }

    float tmp[12];
    #pragma unroll
    for (int r = 0; r < 12; r++) tmp[r] = kap[r] * sr[r];

    // out[o] = sum_cp sum_q WL[4o+q][cp] * U_q[cp],  U_q[cp] = sum_p tmp[3q+p]*theta[(p+cp)%48]
    float out[48];
    #pragma unroll
    for (int o = 0; o < 48; o++) out[o] = 0.f;
    for (int cp = 0; cp < 48; cp++) {
        int i1 = (cp + 1 < 48) ? cp + 1 : cp - 47;
        int i2 = (cp + 2 < 48) ? cp + 2 : cp - 46;
        float t0 = th_s[tid][cp], t1 = th_s[tid][i1], t2 = th_s[tid][i2];
        float u0 = tmp[0]*t0 + tmp[1]*t1 + tmp[2]*t2;
        float u1 = tmp[3]*t0 + tmp[4]*t1 + tmp[5]*t2;
        float u2 = tmp[6]*t0 + tmp[7]*t1 + tmp[8]*t2;
        float u3 = tmp[9]*t0 + tmp[10]*t1 + tmp[11]*t2;
        const float* wl = wlt + cp * 192;
        #pragma unroll
        for (int o = 0; o < 48; o++) {
            float a = out[o];
            a = fmaf(wl[4*o+0], u0, a);
            a = fmaf(wl[4*o+1], u1, a);
            a = fmaf(wl[4*o+2], u2, a);
            a = fmaf(wl[4*o+3], u3, a);
            out[o] = a;
        }
    }

    // gamma scale + mean over the 8 k-lanes; write 0.5*hNL (combine halves here)
    #pragma unroll
    for (int o = 0; o < 48; o++) {
        float w = gamma * out[o];
        w += __shfl_xor(w, 1, 64);
        w += __shfl_xor(w, 2, 64);
        w += __shfl_xor(w, 4, 64);
        out[o] = w;
    }
    if ((gt & 7) == 0) {
        #pragma unroll
        for (int o = 0; o < 48; o++) outp[o*NPIX + n] = 0.0625f * out[o];  // 0.5 * mean(=1/8)
    }
}

// ---------------- conv 3x3 (reflect pad), adds 0.5*hL + bias into d_out ----------------
__global__ __launch_bounds__(256) void conv_kernel(const float* h, const float* wc,
                                                   const float* bias, float* outp) {
    int o  = blockIdx.x / 40;
    int yg = blockIdx.x % 40;
    int ty = threadIdx.x >> 6;
    int tx = threadIdx.x & 63;
    int y = yg * 4 + ty;
    const float* wo = wc + o * 432;
    float bo = bias[o];
    for (int xb = 0; xb < 3; xb++) {
        int x = xb * 64 + tx;
        if (x < WWID) {
            float acc = 0.f;
            for (int c = 0; c < 48; c++) {
                const float* hc = h + c * NPIX;
                #pragma unroll
                for (int dy = 0; dy < 3; dy++) {
                    int yy = y + dy - 1;
                    yy = yy < 0 ? -yy : (yy >= HH ? 2*HH - 2 - yy : yy);
                    const float* hr = hc + yy * WWID;
                    const float* w3 = wo + c*9 + dy*3;
                    #pragma unroll
                    for (int dx = 0; dx < 3; dx++) {
                        int xx = x + dx - 1;
                        xx = xx < 0 ? -xx : (xx >= WWID ? 2*WWID - 2 - xx : xx);
                        acc = fmaf(hr[xx], w3[dx], acc);
                    }
                }
            }
            int idx = o * NPIX + y * WWID + x;
            outp[idx] = outp[idx] + 0.5f * acc + bo;
        }
    }
}

extern "C" void kernel_launch(void* const* d_in, const int* in_sizes, int n_in,
                              void* d_out, int out_size, void* d_ws, size_t ws_size,
                              hipStream_t stream) {
    const float* h    = (const float*)d_in[0];
    const float* W0   = (const float*)d_in[1];
    const float* b0   = (const float*)d_in[2];
    const float* WL   = (const float*)d_in[3];
    const float* WR   = (const float*)d_in[4];
    const float* Wk   = (const float*)d_in[5];
    const float* bk   = (const float*)d_in[6];
    const float* Wc   = (const float*)d_in[7];
    const float* bias = (const float*)d_in[8];

    float* ws   = (float*)d_ws;
    int*   edge = (int*)(ws + OFF_EDGE);
    float* outp = (float*)d_out;

    prep_kernel<<<dim3(16), dim3(256), 0, stream>>>(W0, b0, WL, WR, Wk, bk, ws);
    topk_kernel<<<dim3(200), dim3(128), 0, stream>>>(h, edge);
    ecc_kernel<<<dim3(1600), dim3(128), 0, stream>>>(h, ws, edge, outp);
    conv_kernel<<<dim3(1920), dim3(256), 0, stream>>>(h, Wc, bias, outp);
}

// Round 3
// 636.902 us; speedup vs baseline: 1.5035x; 1.5035x over previous
//
#include <hip/hip_runtime.h>

#define CC    48
#define HH    160
#define WWID  160
#define NPIX  25600
#define KK    8

typedef unsigned short u16;

// ws float layout offsets
#define OFF_W0T   0        // 2304   w0t[c*48+o] = W0[o][c]
#define OFF_B0    2304     // 48
#define OFF_WRT   2352     // 9216   wrt[cp*192 + i] = WR[i][cp]
#define OFF_WLT   11568    // 9216   wlt[cp*192 + i] = WL[i][cp]
#define OFF_WKT   20784    // 576    wkt[c*12+r] = Wk[r][c]
#define OFF_BK    21360    // 12
#define OFF_EDGE  21372    // int[204800]
#define OFF_PARTD 226172   // float[25600*64]
#define OFF_PARTI 1864572  // u16[25600*64] (819200 floats of space)
// total floats = 2,683,772  (~10.3 MB)

__global__ void prep_kernel(const float* W0, const float* b0, const float* WL,
                            const float* WR, const float* Wk, const float* bk,
                            float* ws) {
    float* w0t  = ws + OFF_W0T;
    float* b0f  = ws + OFF_B0;
    float* wrt  = ws + OFF_WRT;
    float* wlt  = ws + OFF_WLT;
    float* wkt  = ws + OFF_WKT;
    float* bkf  = ws + OFF_BK;
    int t = blockIdx.x * 256 + threadIdx.x;
    int stride = gridDim.x * 256;
    for (int i = t; i < 2304; i += stride) { int c = i / 48, o = i % 48; w0t[i] = W0[o*48 + c]; }
    for (int i = t; i < 9216; i += stride) {
        int cp = i / 192, r = i % 192;
        wrt[i] = WR[r*48 + cp];
        wlt[i] = WL[r*48 + cp];
    }
    for (int i = t; i < 576; i += stride) { int c = i / 12, r = i % 12; wkt[i] = Wk[r*48 + c]; }
    for (int i = t; i < 48; i += stride) { b0f[i] = b0[i]; }
    for (int i = t; i < 12; i += stride) { bkf[i] = bk[i]; }
}

// ---- topk stage 1: per (window, 256-pixel group, 128-candidate chunk) partial top8 ----
__global__ __launch_bounds__(128) void topk_part(const float* h, float* part_d, u16* part_i) {
    __shared__ float fs[128][52];   // candidate features (52-f rows: 16B-aligned)
    __shared__ float sqs[128];
    int b   = blockIdx.x;
    int ch  = b & 7;
    int pg  = (b >> 3) & 3;
    int win = b >> 5;
    int wi = win / 5, wj = win % 5;
    int tid = threadIdx.x;

    // stage this chunk's 128 candidates
    int ml = ch * 128 + tid;
    int mg = (wi*32 + (ml >> 5)) * WWID + (wj*32 + (ml & 31));
    {
        float s = 0.f;
        #pragma unroll
        for (int c = 0; c < 48; c++) {
            float v = h[c*NPIX + mg];
            fs[tid][c] = v;
            s += v * v;
        }
        sqs[tid] = s;
    }
    __syncthreads();

    // own two pixels (same window row, adjacent cols)
    int nl0 = pg * 256 + tid * 2;
    int rn = nl0 >> 5, cn0 = nl0 & 31;
    int n0 = (wi*32 + rn) * WWID + (wj*32 + cn0);
    float f0[48], f1[48];
    #pragma unroll
    for (int c = 0; c < 48; c++) { f0[c] = h[c*NPIX + n0]; f1[c] = h[c*NPIX + n0 + 1]; }

    float d80[8], d81[8]; int i80[8], i81[8];
    #pragma unroll
    for (int s = 0; s < 8; s++) { d80[s] = 3.0e38f; d81[s] = 3.0e38f; i80[s] = 0; i81[s] = 0; }
    float w0 = 3.0e38f, w1 = 3.0e38f;

    for (int j = 0; j < 128; j++) {
        int mlj = ch * 128 + j;
        int rm = mlj >> 5, cm = mlj & 31;
        float a0 = 0.f, a1 = 0.f, a2 = 0.f, a3 = 0.f;   // dot0 partials
        float b0_ = 0.f, b1_ = 0.f, b2_ = 0.f, b3_ = 0.f; // dot1 partials
        #pragma unroll
        for (int c4 = 0; c4 < 12; c4++) {
            float4 q = *(const float4*)&fs[j][c4*4];
            a0 = fmaf(f0[c4*4+0], q.x, a0); a1 = fmaf(f0[c4*4+1], q.y, a1);
            a2 = fmaf(f0[c4*4+2], q.z, a2); a3 = fmaf(f0[c4*4+3], q.w, a3);
            b0_ = fmaf(f1[c4*4+0], q.x, b0_); b1_ = fmaf(f1[c4*4+1], q.y, b1_);
            b2_ = fmaf(f1[c4*4+2], q.z, b2_); b3_ = fmaf(f1[c4*4+3], q.w, b3_);
        }
        float sq = sqs[j];
        float d0 = sq - 2.f * ((a0 + a1) + (a2 + a3));
        float d1 = sq - 2.f * ((b0_ + b1_) + (b2_ + b3_));
        int dr = rn - rm; dr = dr < 0 ? -dr : dr;
        int dc0 = cn0 - cm; dc0 = dc0 < 0 ? -dc0 : dc0;
        int dc1 = cn0 + 1 - cm; dc1 = dc1 < 0 ? -dc1 : dc1;
        bool ok0 = !(dr <= 1 && dc0 <= 1);
        bool ok1 = !(dr <= 1 && dc1 <= 1);
        if (ok0 && d0 < w0) {
            bool done = false;
            #pragma unroll
            for (int s = 0; s < 8; s++) {
                bool hit = (!done) && (d80[s] == w0);
                if (hit) { d80[s] = d0; i80[s] = mlj; done = true; }
            }
            w0 = d80[0];
            #pragma unroll
            for (int s = 1; s < 8; s++) w0 = fmaxf(w0, d80[s]);
        }
        if (ok1 && d1 < w1) {
            bool done = false;
            #pragma unroll
            for (int s = 0; s < 8; s++) {
                bool hit = (!done) && (d81[s] == w1);
                if (hit) { d81[s] = d1; i81[s] = mlj; done = true; }
            }
            w1 = d81[0];
            #pragma unroll
            for (int s = 1; s < 8; s++) w1 = fmaxf(w1, d81[s]);
        }
    }

    long base0 = (long)n0 * 64 + ch * 8;
    long base1 = (long)(n0 + 1) * 64 + ch * 8;
    #pragma unroll
    for (int s = 0; s < 8; s++) {
        part_d[base0 + s] = d80[s];
        part_i[base0 + s] = (u16)i80[s];
        part_d[base1 + s] = d81[s];
        part_i[base1 + s] = (u16)i81[s];
    }
}

// ---- topk stage 2: merge 8 chunks x 8 -> final top8, emit global edge indices ----
__global__ __launch_bounds__(256) void topk_merge(const float* part_d, const u16* part_i,
                                                  int* edge) {
    int n = blockIdx.x * 256 + threadIdx.x;   // flat image pixel
    const float* pd = part_d + (long)n * 64;
    const u16*   pi = part_i + (long)n * 64;
    float d8[8]; int i8[8];
    #pragma unroll
    for (int s = 0; s < 8; s++) { d8[s] = 3.0e38f; i8[s] = 0; }
    float dworst = 3.0e38f;
    for (int j = 0; j < 64; j++) {
        float d = pd[j];
        if (d < dworst) {
            int idx = (int)pi[j];
            bool done = false;
            #pragma unroll
            for (int s = 0; s < 8; s++) {
                bool hit = (!done) && (d8[s] == dworst);
                if (hit) { d8[s] = d; i8[s] = idx; done = true; }
            }
            dworst = d8[0];
            #pragma unroll
            for (int s = 1; s < 8; s++) dworst = fmaxf(dworst, d8[s]);
        }
    }
    int y = n / WWID, x = n % WWID;
    int wy = (y >> 5) << 5, wx = (x >> 5) << 5;   // window origin
    #pragma unroll
    for (int s = 0; s < 8; s++) {
        int ml = i8[s];
        edge[n*8 + s] = (wy + (ml >> 5)) * WWID + (wx + (ml & 31));
    }
}

// ---------------- ecc: one lane per edge; writes 0.5*hNL into d_out ----------------
__global__ __launch_bounds__(128) void ecc_kernel(const float* h, const float* ws,
                                                  const int* edge, float* outp) {
    const float* w0t = ws + OFF_W0T;
    const float* b0f = ws + OFF_B0;
    const float* wrt = ws + OFF_WRT;
    const float* wlt = ws + OFF_WLT;
    const float* wkt = ws + OFF_WKT;
    const float* bkf = ws + OFF_BK;

    __shared__ float th_s[128][49];   // theta, lane-private row (stride 49: conflict-free rotate reads)

    int tid = threadIdx.x;
    int gt = blockIdx.x * 128 + tid;  // edge id = n*8+k
    int n = gt >> 3;
    int m = edge[gt];

    // phase 1: theta = LReLU(W0 @ label + b0), gamma; vertex kept in registers
    float v[48];
    float th[48];
    #pragma unroll
    for (int o = 0; o < 48; o++) th[o] = 0.f;
    float s2 = 0.f;
    for (int c = 0; c < 48; c++) {
        float vf = h[c*NPIX + m];
        float cf = h[c*NPIX + n];
        v[c] = vf;
        float lc = vf - cf;
        s2 += lc * lc;
        const float* wc = w0t + c*48;
        #pragma unroll
        for (int o = 0; o < 48; o++) th[o] = fmaf(wc[o], lc, th[o]);
    }
    float gamma = expf(-s2 / 10.0f);
    #pragma unroll
    for (int o = 0; o < 48; o++) {
        float x = th[o] + b0f[o];
        th_s[tid][o] = (x >= 0.f) ? x : 0.01f * x;
    }

    // kappa = Wk @ theta + bk
    float kap[12];
    #pragma unroll
    for (int r = 0; r < 12; r++) kap[r] = bkf[r];
    for (int c = 0; c < 48; c++) {
        float t = th_s[tid][c];
        const float* wkc = wkt + c*12;
        #pragma unroll
        for (int r = 0; r < 12; r++) kap[r] = fmaf(wkc[r], t, kap[r]);
    }

    // sR[3q+p] = sum_cp theta[(p+cp)%48] * vt_q[cp],  vt_q[cp] = sum_c v[c]*WR[4c+q][cp]
    float sr[12];
    #pragma unroll
    for (int r = 0; r < 12; r++) sr[r] = 0.f;
    for (int cp = 0; cp < 48; cp++) {
        int i1 = (cp + 1 < 48) ? cp + 1 : cp - 47;
        int i2 = (cp + 2 < 48) ? cp + 2 : cp - 46;
        float t0 = th_s[tid][cp], t1 = th_s[tid][i1], t2 = th_s[tid][i2];
        const float* wr = wrt + cp * 192;
        float vt0 = 0.f, vt1 = 0.f, vt2 = 0.f, vt3 = 0.f;
        #pragma unroll
        for (int c = 0; c < 48; c++) {
            float vc = v[c];
            vt0 = fmaf(wr[4*c+0], vc, vt0);
            vt1 = fmaf(wr[4*c+1], vc, vt1);
            vt2 = fmaf(wr[4*c+2], vc, vt2);
            vt3 = fmaf(wr[4*c+3], vc, vt3);
        }
        sr[0] = fmaf(t0, vt0, sr[0]); sr[1]  = fmaf(t1, vt0, sr[1]);  sr[2]  = fmaf(t2, vt0, sr[2]);
        sr[3] = fmaf(t0, vt1, sr[3]); sr[4]  = fmaf(t1, vt1, sr[4]);  sr[5]  = fmaf(t2, vt1, sr[5]);
        sr[6] = fmaf(t0, vt2, sr[6]); sr[7]  = fmaf(t1, vt2, sr[7]);  sr[8]  = fmaf(t2, vt2, sr[8]);
        sr[9] = fmaf(t0, vt3, sr[9]); sr[10] = fmaf(t1, vt3, sr[10]); sr[11] = fmaf(t2, vt3, sr[11]);
    }

    float tmp[12];
    #pragma unroll
    for (int r = 0; r < 12; r++) tmp[r] = kap[r] * sr[r];

    // out[o] = sum_cp sum_q WL[4o+q][cp] * U_q[cp],  U_q[cp] = sum_p tmp[3q+p]*theta[(p+cp)%48]
    float out[48];
    #pragma unroll
    for (int o = 0; o < 48; o++) out[o] = 0.f;
    for (int cp = 0; cp < 48; cp++) {
        int i1 = (cp + 1 < 48) ? cp + 1 : cp - 47;
        int i2 = (cp + 2 < 48) ? cp + 2 : cp - 46;
        float t0 = th_s[tid][cp], t1 = th_s[tid][i1], t2 = th_s[tid][i2];
        float u0 = tmp[0]*t0 + tmp[1]*t1 + tmp[2]*t2;
        float u1 = tmp[3]*t0 + tmp[4]*t1 + tmp[5]*t2;
        float u2 = tmp[6]*t0 + tmp[7]*t1 + tmp[8]*t2;
        float u3 = tmp[9]*t0 + tmp[10]*t1 + tmp[11]*t2;
        const float* wl = wlt + cp * 192;
        #pragma unroll
        for (int o = 0; o < 48; o++) {
            float a = out[o];
            a = fmaf(wl[4*o+0], u0, a);
            a = fmaf(wl[4*o+1], u1, a);
            a = fmaf(wl[4*o+2], u2, a);
            a = fmaf(wl[4*o+3], u3, a);
            out[o] = a;
        }
    }

    // gamma scale + mean over the 8 k-lanes; write 0.5*hNL (combine halves here)
    #pragma unroll
    for (int o = 0; o < 48; o++) {
        float w = gamma * out[o];
        w += __shfl_xor(w, 1, 64);
        w += __shfl_xor(w, 2, 64);
        w += __shfl_xor(w, 4, 64);
        out[o] = w;
    }
    if ((gt & 7) == 0) {
        #pragma unroll
        for (int o = 0; o < 48; o++) outp[o*NPIX + n] = 0.0625f * out[o];  // 0.5 * mean(=1/8)
    }
}

// ---------------- conv 3x3 (reflect pad), adds 0.5*hL + bias into d_out ----------------
__global__ __launch_bounds__(256) void conv_kernel(const float* h, const float* wc,
                                                   const float* bias, float* outp) {
    int o  = blockIdx.x / 40;
    int yg = blockIdx.x % 40;
    int ty = threadIdx.x >> 6;
    int tx = threadIdx.x & 63;
    int y = yg * 4 + ty;
    const float* wo = wc + o * 432;
    float bo = bias[o];
    for (int xb = 0; xb < 3; xb++) {
        int x = xb * 64 + tx;
        if (x < WWID) {
            float acc = 0.f;
            for (int c = 0; c < 48; c++) {
                const float* hc = h + c * NPIX;
                #pragma unroll
                for (int dy = 0; dy < 3; dy++) {
                    int yy = y + dy - 1;
                    yy = yy < 0 ? -yy : (yy >= HH ? 2*HH - 2 - yy : yy);
                    const float* hr = hc + yy * WWID;
                    const float* w3 = wo + c*9 + dy*3;
                    #pragma unroll
                    for (int dx = 0; dx < 3; dx++) {
                        int xx = x + dx - 1;
                        xx = xx < 0 ? -xx : (xx >= WWID ? 2*WWID - 2 - xx : xx);
                        acc = fmaf(hr[xx], w3[dx], acc);
                    }
                }
            }
            int idx = o * NPIX + y * WWID + x;
            outp[idx] = outp[idx] + 0.5f * acc + bo;
        }
    }
}

extern "C" void kernel_launch(void* const* d_in, const int* in_sizes, int n_in,
                              void* d_out, int out_size, void* d_ws, size_t ws_size,
                              hipStream_t stream) {
    const float* h    = (const float*)d_in[0];
    const float* W0   = (const float*)d_in[1];
    const float* b0   = (const float*)d_in[2];
    const float* WL   = (const float*)d_in[3];
    const float* WR   = (const float*)d_in[4];
    const float* Wk   = (const float*)d_in[5];
    const float* bk   = (const float*)d_in[6];
    const float* Wc   = (const float*)d_in[7];
    const float* bias = (const float*)d_in[8];

    float* ws     = (float*)d_ws;
    int*   edge   = (int*)(ws + OFF_EDGE);
    float* part_d = ws + OFF_PARTD;
    u16*   part_i = (u16*)(ws + OFF_PARTI);
    float* outp   = (float*)d_out;

    prep_kernel<<<dim3(16), dim3(256), 0, stream>>>(W0, b0, WL, WR, Wk, bk, ws);
    topk_part<<<dim3(800), dim3(128), 0, stream>>>(h, part_d, part_i);
    topk_merge<<<dim3(100), dim3(256), 0, stream>>>(part_d, part_i, edge);
    ecc_kernel<<<dim3(1600), dim3(128), 0, stream>>>(h, ws, edge, outp);
    conv_kernel<<<dim3(1920), dim3(256), 0, stream>>>(h, Wc, bias, outp);
}